// Round 9
// baseline (421.925 us; speedup 1.0000x reference)
//
#include <hip/hip_runtime.h>

#define T_LEN 1024
#define B_TOTAL 8192

typedef _Float16 f16x8 __attribute__((ext_vector_type(8)));
typedef float f32x4 __attribute__((ext_vector_type(4)));

// Pade(7,6) tanh: 1 rcp, 0 exp. |err| < ~2e-4 for |x| <= 5 (pre-activations
// here are bounded ~|b|+|Wx|+|W||h| < ~6 worst case, ~3 typical).
__device__ __forceinline__ float pade_tanh(float x) {
    const float t = x * x;
    float n = 378.0f + t;
    n = fmaf(t, n, 17325.0f);
    n = fmaf(t, n, 135135.0f);          // N(t); tanh = x*N/(D)
    float d = fmaf(t, 28.0f, 3150.0f);
    d = fmaf(t, d, 62370.0f);
    d = fmaf(t, d, 135135.0f);          // D(t)
    const float r = __builtin_amdgcn_rcpf(d);
    return x * n * r;
}

#define MFMA(a, b, c) __builtin_amdgcn_mfma_f32_16x16x32_f16((a), (b), (c), 0, 0, 0)

// Single wave per 16 batches, TIME-SKEWED layers, pure-register recurrence.
// Per step: h1(t+1) (layer 1, uses x_{t+1}) and h2(t) (layer 2, uses h1(t),
// h2(t-1)) are computed CONCURRENTLY -> 16 independent tanhs, per-step chain
// = max(layer chains) instead of their sum. Layer-2's two MFMAs go to
// separate accumulators (no C-chain) and are summed on the VALU.
// Unit-relabeling (round-6-verified): A-row m <- weight row 8*(m>>2)+(m&3)
// (lo) / +4 (hi); lane (bl,g)'s D regs are storage slots {8g+r, 8g+4+r} =
// exactly its next B-fragment k-slots -> no transpose anywhere.
__global__ __launch_bounds__(64, 1) void rnn_skew_kernel(
    const float* __restrict__ x,     const float* __restrict__ h0,
    const float* __restrict__ W_ih0, const float* __restrict__ W_hh0,
    const float* __restrict__ b_ih0, const float* __restrict__ b_hh0,
    const float* __restrict__ W_ih1, const float* __restrict__ W_hh1,
    const float* __restrict__ b_ih1, const float* __restrict__ b_hh1,
    const float* __restrict__ W_out, const float* __restrict__ b_out,
    float* __restrict__ out)
{
    const int lane = threadIdx.x;          // 0..63
    const int bl   = lane & 15;            // batch column (n-index / A-row)
    const int hi   = lane >> 4;            // lane quad g
    const int s0   = hi * 8;               // storage-slot base
    const int gb   = blockIdx.x * 16 + bl; // global batch

    const int ulo = 8 * (bl >> 2) + (bl & 3); // weight row for A-lo row bl
    const int uhi = ulo + 4;

    // --- stationary A fragments (weights, unit-permuted rows) ---
    f16x8 whh0_lo, whh0_hi, wih1_lo, wih1_hi, whh1_lo, whh1_hi, wout_f;
#pragma unroll
    for (int e = 0; e < 8; ++e) {
        whh0_lo[e] = (_Float16)W_hh0[ulo * 32 + s0 + e];
        whh0_hi[e] = (_Float16)W_hh0[uhi * 32 + s0 + e];
        wih1_lo[e] = (_Float16)W_ih1[ulo * 32 + s0 + e];
        wih1_hi[e] = (_Float16)W_ih1[uhi * 32 + s0 + e];
        whh1_lo[e] = (_Float16)W_hh1[ulo * 32 + s0 + e];
        whh1_hi[e] = (_Float16)W_hh1[uhi * 32 + s0 + e];
        wout_f[e]  = (bl == 0) ? (_Float16)W_out[s0 + e] : (_Float16)0.0f;
    }

    // --- per-lane D-layout constants: units s0+r (lo regs), s0+4+r (hi) ---
    f32x4 c0lo, c0hi, c1lo, c1hi, wi0lo, wi0hi;
#pragma unroll
    for (int r = 0; r < 4; ++r) {
        const int u = s0 + r, uh = s0 + 4 + r;
        c0lo[r] = b_ih0[u]  + b_hh0[u];
        c0hi[r] = b_ih0[uh] + b_hh0[uh];
        c1lo[r] = b_ih1[u]  + b_hh1[u];
        c1hi[r] = b_ih1[uh] + b_hh1[uh];
        wi0lo[r] = W_ih0[u];
        wi0hi[r] = W_ih0[uh];
    }
    const float bo = b_out[0];
    const f32x4 zero4 = {0.f, 0.f, 0.f, 0.f};

    // --- initial states ---
    f16x8 Y1, Y2; // Y1 = h1(t) [after prologue], Y2 = h2(t-1)
#pragma unroll
    for (int e = 0; e < 8; ++e) {
        Y1[e] = (_Float16)h0[(size_t)gb * 32 + s0 + e];
        Y2[e] = (_Float16)h0[(size_t)(B_TOTAL + gb) * 32 + s0 + e];
    }

    const float* xp = x + (size_t)gb * T_LEN;
    float* yp = out + (size_t)gb * T_LEN;

    // --- prologue: h1(0) = tanh(c0 + wih0*x0 + W_hh0 . h1(-1)) ---
    float4 xq = *(const float4*)(xp); // x[0..3]
    {
        f32x4 plo, phi;
#pragma unroll
        for (int r = 0; r < 4; ++r) {
            plo[r] = fmaf(xq.x, wi0lo[r], c0lo[r]);
            phi[r] = fmaf(xq.x, wi0hi[r], c0hi[r]);
        }
        const f32x4 dlo = MFMA(whh0_lo, Y1, plo);
        const f32x4 dhi = MFMA(whh0_hi, Y1, phi);
#pragma unroll
        for (int r = 0; r < 4; ++r) {
            Y1[r]     = (_Float16)pade_tanh(dlo[r]);
            Y1[4 + r] = (_Float16)pade_tanh(dhi[r]);
        }
    }

    // --- main loop: quads m=0..254, t=4m+u, computes h1(t+1) || h2(t), y(t) ---
    for (int m = 0; m < 254 + 1; ++m) {
        const float4 xqn = *(const float4*)(xp + m * 4 + 4); // x[4m+4..4m+7]
        float yq0, yq1, yq2, yq3;
#pragma unroll
        for (int u = 0; u < 4; ++u) {
            const float xt1 = (u == 0) ? xq.y : (u == 1) ? xq.z : (u == 2) ? xq.w : xqn.x;

            // layer 1 (next step): d1 = W_hh0 . h1(t) + (c0 + wih0*x_{t+1})
            f32x4 plo, phi;
#pragma unroll
            for (int r = 0; r < 4; ++r) {
                plo[r] = fmaf(xt1, wi0lo[r], c0lo[r]);
                phi[r] = fmaf(xt1, wi0hi[r], c0hi[r]);
            }
            const f32x4 d1lo = MFMA(whh0_lo, Y1, plo);
            const f32x4 d1hi = MFMA(whh0_hi, Y1, phi);
            // layer 2 (current step): independent accumulators, no C-chain
            const f32x4 d2alo = MFMA(whh1_lo, Y2, c1lo);
            const f32x4 d2ahi = MFMA(whh1_hi, Y2, c1hi);
            const f32x4 d2blo = MFMA(wih1_lo, Y1, zero4);
            const f32x4 d2bhi = MFMA(wih1_hi, Y1, zero4);

            // 16 independent tanhs (interleaved)
            f16x8 Y1n, Y2n;
#pragma unroll
            for (int r = 0; r < 4; ++r) {
                Y1n[r]     = (_Float16)pade_tanh(d1lo[r]);
                Y2n[r]     = (_Float16)pade_tanh(d2alo[r] + d2blo[r]);
                Y1n[4 + r] = (_Float16)pade_tanh(d1hi[r]);
                Y2n[4 + r] = (_Float16)pade_tanh(d2ahi[r] + d2bhi[r]);
            }

            // y head (off-chain): W_out in A-row 0 -> y[bl] = D[m=0][bl]
            const f32x4 d3 = MFMA(wout_f, Y2n, zero4);
            const float yv = d3[0] + bo;
            if (u == 0) yq0 = yv; else if (u == 1) yq1 = yv; else if (u == 2) yq2 = yv; else yq3 = yv;

            Y1 = Y1n;
            Y2 = Y2n;
        }
        if (hi == 0) {
            float4 yo; yo.x = yq0; yo.y = yq1; yo.z = yq2; yo.w = yq3;
            *(float4*)(yp + m * 4) = yo;
        }
        xq = xqn;
    }

    // --- epilogue: t=1020..1023 (xq = x[1020..1023]); layer1 only while t+1<=1023 ---
    float h1f[8], h2f[8];
    {
        float yq0, yq1, yq2, yq3;
#pragma unroll
        for (int u = 0; u < 4; ++u) {
            // layer 2 + head for t = 1020+u
            const f32x4 d2alo = MFMA(whh1_lo, Y2, c1lo);
            const f32x4 d2ahi = MFMA(whh1_hi, Y2, c1hi);
            const f32x4 d2blo = MFMA(wih1_lo, Y1, zero4);
            const f32x4 d2bhi = MFMA(wih1_hi, Y1, zero4);
            f16x8 Y2n;
#pragma unroll
            for (int r = 0; r < 4; ++r) {
                h2f[r]     = pade_tanh(d2alo[r] + d2blo[r]);
                h2f[4 + r] = pade_tanh(d2ahi[r] + d2bhi[r]);
                Y2n[r]     = (_Float16)h2f[r];
                Y2n[4 + r] = (_Float16)h2f[4 + r];
            }
            const f32x4 d3 = MFMA(wout_f, Y2n, zero4);
            const float yv = d3[0] + bo;
            if (u == 0) yq0 = yv; else if (u == 1) yq1 = yv; else if (u == 2) yq2 = yv; else yq3 = yv;

            if (u < 3) { // h1(t+1), t+1 <= 1023
                const float xt1 = (u == 0) ? xq.y : (u == 1) ? xq.z : xq.w;
                f32x4 plo, phi;
#pragma unroll
                for (int r = 0; r < 4; ++r) {
                    plo[r] = fmaf(xt1, wi0lo[r], c0lo[r]);
                    phi[r] = fmaf(xt1, wi0hi[r], c0hi[r]);
                }
                const f32x4 d1lo = MFMA(whh0_lo, Y1, plo);
                const f32x4 d1hi = MFMA(whh0_hi, Y1, phi);
                f16x8 Y1n;
#pragma unroll
                for (int r = 0; r < 4; ++r) {
                    h1f[r]     = pade_tanh(d1lo[r]);
                    h1f[4 + r] = pade_tanh(d1hi[r]);
                    Y1n[r]     = (_Float16)h1f[r];
                    Y1n[4 + r] = (_Float16)h1f[4 + r];
                }
                Y1 = Y1n;
            }
            Y2 = Y2n;
        }
        if (hi == 0) {
            float4 yo; yo.x = yq0; yo.y = yq1; yo.z = yq2; yo.w = yq3;
            *(float4*)(yp + 1020) = yo;
        }
    }

    // --- final hidden states: h_state [2, B, 32] (f32 trajectory values) ---
    float* hs = out + (size_t)B_TOTAL * T_LEN;
#pragma unroll
    for (int r = 0; r < 4; ++r) {
        hs[(size_t)gb * 32 + s0 + r]                 = h1f[r];
        hs[(size_t)gb * 32 + s0 + 4 + r]             = h1f[4 + r];
        hs[(size_t)(B_TOTAL + gb) * 32 + s0 + r]     = h2f[r];
        hs[(size_t)(B_TOTAL + gb) * 32 + s0 + 4 + r] = h2f[4 + r];
    }
}

extern "C" void kernel_launch(void* const* d_in, const int* in_sizes, int n_in,
                              void* d_out, int out_size, void* d_ws, size_t ws_size,
                              hipStream_t stream) {
    const float* x     = (const float*)d_in[0];
    const float* h0    = (const float*)d_in[1];
    const float* W_ih0 = (const float*)d_in[2];
    const float* W_hh0 = (const float*)d_in[3];
    const float* b_ih0 = (const float*)d_in[4];
    const float* b_hh0 = (const float*)d_in[5];
    const float* W_ih1 = (const float*)d_in[6];
    const float* W_hh1 = (const float*)d_in[7];
    const float* b_ih1 = (const float*)d_in[8];
    const float* b_hh1 = (const float*)d_in[9];
    const float* W_out = (const float*)d_in[10];
    const float* b_out = (const float*)d_in[11];
    float* out = (float*)d_out;

    dim3 grid(B_TOTAL / 16); // 512 waves, 1 wave/block, 16 batches each
    dim3 block(64);
    rnn_skew_kernel<<<grid, block, 0, stream>>>(x, h0, W_ih0, W_hh0, b_ih0, b_hh0,
                                                W_ih1, W_hh1, b_ih1, b_hh1,
                                                W_out, b_out, out);
}